// Round 6
// baseline (56.089 us; speedup 1.0000x reference)
//
#include <hip/hip_runtime.h>

#define NBLOCKS 2048
#define NTHREADS 256

typedef float fvec4 __attribute__((ext_vector_type(4)));

__global__ __launch_bounds__(NTHREADS) void pareto_partial(
    const float* __restrict__ y,
    const float* __restrict__ alpha,
    const int* __restrict__ xm_p,
    float* __restrict__ partials,
    int n, int thresh4)
{
    const float xm = (float)xm_p[0];
    const int n4 = n >> 2;
    const fvec4* __restrict__ y4 = (const fvec4*)y;
    const fvec4* __restrict__ a4 = (const fvec4*)alpha;

    float acc = 0.0f;
    const int stride = gridDim.x * blockDim.x;
    const int gid = blockIdx.x * blockDim.x + threadIdx.x;

    // Region 1: first ~75% of both arrays — normal loads, intended to stay
    // L3-resident across graph replays (192 MiB < 256 MiB L3 capacity).
    for (int i = gid; i < thresh4; i += stride) {
        fvec4 yv = y4[i];
        fvec4 av = a4[i];
        if (yv.x > 0.0f) acc += __logf(av.x) * xm - (av.x + 1.0f) * __logf(yv.x);
        if (yv.y > 0.0f) acc += __logf(av.y) * xm - (av.y + 1.0f) * __logf(yv.y);
        if (yv.z > 0.0f) acc += __logf(av.z) * xm - (av.z + 1.0f) * __logf(yv.z);
        if (yv.w > 0.0f) acc += __logf(av.w) * xm - (av.w + 1.0f) * __logf(yv.w);
    }

    // Region 2: last ~25% — nontemporal (no-allocate) loads: stream from HBM
    // without evicting region 1 from the Infinity Cache.
    for (int i = thresh4 + gid; i < n4; i += stride) {
        fvec4 yv = __builtin_nontemporal_load(y4 + i);
        fvec4 av = __builtin_nontemporal_load(a4 + i);
        if (yv.x > 0.0f) acc += __logf(av.x) * xm - (av.x + 1.0f) * __logf(yv.x);
        if (yv.y > 0.0f) acc += __logf(av.y) * xm - (av.y + 1.0f) * __logf(yv.y);
        if (yv.z > 0.0f) acc += __logf(av.z) * xm - (av.z + 1.0f) * __logf(yv.z);
        if (yv.w > 0.0f) acc += __logf(av.w) * xm - (av.w + 1.0f) * __logf(yv.w);
    }

    // tail (n not multiple of 4) — one thread
    if (blockIdx.x == 0 && threadIdx.x == 0) {
        for (int i = n4 << 2; i < n; ++i) {
            float yv = y[i];
            if (yv > 0.0f) {
                float av = alpha[i];
                acc += __logf(av) * xm - (av + 1.0f) * __logf(yv);
            }
        }
    }

    // wave-64 reduction
    #pragma unroll
    for (int off = 32; off > 0; off >>= 1)
        acc += __shfl_down(acc, off, 64);

    __shared__ float wsum[NTHREADS / 64];
    const int lane = threadIdx.x & 63;
    const int wid  = threadIdx.x >> 6;
    if (lane == 0) wsum[wid] = acc;
    __syncthreads();
    if (threadIdx.x == 0) {
        float s = 0.0f;
        #pragma unroll
        for (int w = 0; w < NTHREADS / 64; ++w) s += wsum[w];
        partials[blockIdx.x] = s;
    }
}

// single-wave final reduction: no LDS, no barriers, fixed-order double sum
__global__ __launch_bounds__(64) void pareto_final(
    const float* __restrict__ partials,
    float* __restrict__ out,
    int nb)
{
    const int lane = threadIdx.x;
    double acc = 0.0;
    for (int i = lane; i < nb; i += 64)
        acc += (double)partials[i];

    #pragma unroll
    for (int off = 32; off > 0; off >>= 1)
        acc += __shfl_down(acc, off, 64);

    if (lane == 0) out[0] = (float)(-acc);
}

extern "C" void kernel_launch(void* const* d_in, const int* in_sizes, int n_in,
                              void* d_out, int out_size, void* d_ws, size_t ws_size,
                              hipStream_t stream)
{
    const float* y     = (const float*)d_in[0];
    const float* alpha = (const float*)d_in[1];
    const int*   xm    = (const int*)d_in[2];
    float* out = (float*)d_out;
    float* partials = (float*)d_ws;   // NBLOCKS floats = 8 KB scratch

    const int n = in_sizes[0];
    int n4 = n >> 2;
    int grid = (n4 + NTHREADS - 1) / NTHREADS;
    if (grid > NBLOCKS) grid = NBLOCKS;
    if (grid < 1) grid = 1;

    // Keep first 75% of each array cacheable (2 * 0.75 * 128 MiB = 192 MiB
    // < 256 MiB L3); stream the last 25% nontemporally.
    int thresh4 = (n4 >> 2) * 3;

    pareto_partial<<<grid, NTHREADS, 0, stream>>>(y, alpha, xm, partials, n, thresh4);
    pareto_final<<<1, 64, 0, stream>>>(partials, out, grid);
}

// Round 7
// 52.250 us; speedup vs baseline: 1.0735x; 1.0735x over previous
//
#include <hip/hip_runtime.h>

#define NBLOCKS 2048
#define NTHREADS 256

// Final kernel: R1 main-loop structure (simple grid-stride float4, VGPR=12,
// ~82% occupancy — beats unroll/ILP variants on this TLP-latency-hiding
// kernel), __logf (null A/B vs logf, keeps VALU issue low), two-kernel
// reduction (fused last-block __threadfence pattern was a 2.4x regression:
// chip-wide L2 writeback storms). nt-loads: no L3 steering on gfx950 (R6).
// Roofline: 268.4 MB irreducible reads, ~50% L3-served (working set == L3
// capacity), 48.7 us = 5.5 TB/s combined = 87% of 6.3 TB/s copy ceiling.

__global__ __launch_bounds__(NTHREADS) void pareto_partial(
    const float* __restrict__ y,
    const float* __restrict__ alpha,
    const int* __restrict__ xm_p,
    float* __restrict__ partials,
    int n)
{
    const float xm = (float)xm_p[0];
    const int n4 = n >> 2;
    const float4* __restrict__ y4 = (const float4*)y;
    const float4* __restrict__ a4 = (const float4*)alpha;

    float acc = 0.0f;
    const int stride = gridDim.x * blockDim.x;
    for (int i = blockIdx.x * blockDim.x + threadIdx.x; i < n4; i += stride) {
        float4 yv = y4[i];
        float4 av = a4[i];
        if (yv.x > 0.0f) acc += __logf(av.x) * xm - (av.x + 1.0f) * __logf(yv.x);
        if (yv.y > 0.0f) acc += __logf(av.y) * xm - (av.y + 1.0f) * __logf(yv.y);
        if (yv.z > 0.0f) acc += __logf(av.z) * xm - (av.z + 1.0f) * __logf(yv.z);
        if (yv.w > 0.0f) acc += __logf(av.w) * xm - (av.w + 1.0f) * __logf(yv.w);
    }

    // tail (n not multiple of 4) — one thread
    if (blockIdx.x == 0 && threadIdx.x == 0) {
        for (int i = n4 << 2; i < n; ++i) {
            float yv = y[i];
            if (yv > 0.0f) {
                float av = alpha[i];
                acc += __logf(av) * xm - (av + 1.0f) * __logf(yv);
            }
        }
    }

    // wave-64 reduction
    #pragma unroll
    for (int off = 32; off > 0; off >>= 1)
        acc += __shfl_down(acc, off, 64);

    __shared__ float wsum[NTHREADS / 64];
    const int lane = threadIdx.x & 63;
    const int wid  = threadIdx.x >> 6;
    if (lane == 0) wsum[wid] = acc;
    __syncthreads();
    if (threadIdx.x == 0) {
        float s = 0.0f;
        #pragma unroll
        for (int w = 0; w < NTHREADS / 64; ++w) s += wsum[w];
        partials[blockIdx.x] = s;
    }
}

// single-wave final reduction: no LDS, no barriers, fixed-order double sum
__global__ __launch_bounds__(64) void pareto_final(
    const float* __restrict__ partials,
    float* __restrict__ out,
    int nb)
{
    const int lane = threadIdx.x;
    double acc = 0.0;
    for (int i = lane; i < nb; i += 64)
        acc += (double)partials[i];

    #pragma unroll
    for (int off = 32; off > 0; off >>= 1)
        acc += __shfl_down(acc, off, 64);

    if (lane == 0) out[0] = (float)(-acc);
}

extern "C" void kernel_launch(void* const* d_in, const int* in_sizes, int n_in,
                              void* d_out, int out_size, void* d_ws, size_t ws_size,
                              hipStream_t stream)
{
    const float* y     = (const float*)d_in[0];
    const float* alpha = (const float*)d_in[1];
    const int*   xm    = (const int*)d_in[2];
    float* out = (float*)d_out;
    float* partials = (float*)d_ws;   // NBLOCKS floats = 8 KB scratch

    const int n = in_sizes[0];
    int n4 = n >> 2;
    int grid = (n4 + NTHREADS - 1) / NTHREADS;
    if (grid > NBLOCKS) grid = NBLOCKS;
    if (grid < 1) grid = 1;

    pareto_partial<<<grid, NTHREADS, 0, stream>>>(y, alpha, xm, partials, n);
    pareto_final<<<1, 64, 0, stream>>>(partials, out, grid);
}